// Round 14
// baseline (1147.933 us; speedup 1.0000x reference)
//
#include <hip/hip_runtime.h>
#include <hip/hip_bf16.h>

namespace {

constexpr int B  = 32;
constexpr int L  = 100;
constexpr int S  = 501;
constexpr int DK = 64;
constexpr int DE = 128;

typedef __attribute__((ext_vector_type(8))) short short8v;   // 8 bf16 (4 VGPR)
typedef __attribute__((ext_vector_type(4))) float f32x4;
typedef unsigned int u32;

__device__ __forceinline__ float sigm(float x) {
    return __fdividef(1.0f, 1.0f + __expf(-x));
}
// fp32 -> bf16 RNE (one-time staging only)
__device__ __forceinline__ unsigned short f2bf(float f) {
    u32 u = __float_as_uint(f);
    u += 0x7FFFu + ((u >> 16) & 1u);
    return (unsigned short)(u >> 16);
}
// pack two fp32 -> u32 of 2 bf16, round-half-up (4 ops; hot path)
__device__ __forceinline__ u32 pack2(float a, float b) {
    const u32 ua = __float_as_uint(a) + 0x8000u;
    const u32 ub = __float_as_uint(b) + 0x8000u;
    return (ua >> 16) | (ub & 0xFFFF0000u);
}

// ---------------- init: transpose weights (k-major) for pre/y, pred[:,0] ---
__global__ __launch_bounds__(256) void k_init(
    const float* __restrict__ W1, const float* __restrict__ W2,
    const float* __restrict__ W3, const float* __restrict__ W4,
    const float* __restrict__ W5,
    float* __restrict__ W1T, float* __restrict__ W2T, float* __restrict__ W3T,
    float* __restrict__ W4T, float* __restrict__ W5T,
    float* __restrict__ pred)
{
    const int idx = blockIdx.x * 256 + threadIdx.x;
    const int st  = gridDim.x * 256;
    for (int i = idx; i < 64 * 256; i += st) {
        int dd = i >> 8, kk = i & 255;
        W1T[kk * 64 + dd] = W1[i];
        W2T[kk * 64 + dd] = W2[i];
        W3T[kk * 64 + dd] = W3[i];
    }
    for (int i = idx; i < 64 * 192; i += st) {
        int dd = i / 192, kk = i % 192;
        W4T[kk * 64 + dd] = W4[i];
        W5T[kk * 64 + dd] = W5[i];
    }
    if (idx < B) pred[idx * L] = 0.0f;
}

// ---------------- all_learning = concat(e,at,a) @ W1^T + b1 ----------------
__global__ __launch_bounds__(256) void k_all_learning(
    const int* __restrict__ e_data, const int* __restrict__ a_data,
    const int* __restrict__ at_data,
    const float* __restrict__ e_embed, const float* __restrict__ at_embed,
    const float* __restrict__ W1T, const float* __restrict__ b1,
    float* __restrict__ allL)
{
    __shared__ float in_s[4][257];
    const int g = threadIdx.x >> 6;
    const int d = threadIdx.x & 63;
    const int row = blockIdx.x * 4 + g;
    const int e  = e_data[row];
    const int at = at_data[row];
    in_s[g][d]       = e_embed[(size_t)e * DE + d];
    in_s[g][64 + d]  = e_embed[(size_t)e * DE + 64 + d];
    in_s[g][128 + d] = at_embed[(size_t)at * DK + d];
    in_s[g][192 + d] = (float)a_data[row];
    __syncthreads();
    float acc = b1[d];
    #pragma unroll 8
    for (int k = 0; k < 256; ++k) acc += W1T[k * 64 + d] * in_s[g][k];
    allL[row * DK + d] = acc;
}

// ---------------- G2,G3 (non-recurrent parts), G4it, prey ------------------
__global__ __launch_bounds__(256) void k_pre(
    const int* __restrict__ e_data, const int* __restrict__ it_data,
    const float* __restrict__ e_embed, const float* __restrict__ it_embed,
    const float* __restrict__ allL,
    const float* __restrict__ W2T, const float* __restrict__ W3T,
    const float* __restrict__ W4T, const float* __restrict__ W5T,
    const float* __restrict__ b2, const float* __restrict__ b3,
    const float* __restrict__ b4, const float* __restrict__ b5,
    float* __restrict__ G2, float* __restrict__ G3,
    float* __restrict__ G4it, float* __restrict__ prey)
{
    __shared__ float lp[4][64], its[4][64], ln[4][64], ee[4][128];
    const int g = threadIdx.x >> 6;
    const int d = threadIdx.x & 63;
    const int row = blockIdx.x * 4 + g;
    const int t = row % L;
    lp[g][d]  = (t == 0) ? 0.0f : allL[(row - 1) * 64 + d];
    its[g][d] = it_embed[(size_t)it_data[row] * 64 + d];
    ln[g][d]  = allL[row * 64 + d];
    const int e = e_data[row];
    ee[g][d]      = e_embed[(size_t)e * DE + d];
    ee[g][64 + d] = e_embed[(size_t)e * DE + 64 + d];
    __syncthreads();
    float g2 = b2[d], g3 = b3[d], g4 = b4[d], py = b5[d];
    #pragma unroll 4
    for (int k = 0; k < 64; ++k) {
        const float l0 = lp[g][k], i0 = its[g][k], n0 = ln[g][k];
        g2 += W2T[k * 64 + d] * l0 + W2T[(64 + k) * 64 + d] * i0 + W2T[(128 + k) * 64 + d] * n0;
        g3 += W3T[k * 64 + d] * l0 + W3T[(64 + k) * 64 + d] * i0 + W3T[(128 + k) * 64 + d] * n0;
        g4 += W4T[(128 + k) * 64 + d] * i0;
        py += W5T[k * 64 + d] * ee[g][k] + W5T[(64 + k) * 64 + d] * ee[g][64 + k];
    }
    G2[row * 64 + d]   = g2;
    G3[row * 64 + d]   = g3;
    G4it[row * 64 + d] = g4;
    prey[row * 64 + d] = py;
}

// ---------------- persistent recurrence, ABLATION-TEMPLATED ---------------
// MODE bits: 1 = GATES (P1 dots, P2 LG, P3, P4 V + G prefetch)
//            2 = EPI   (h update, hB writes, h_tilde partials/shfl/red4)
//            4 = MFMA  (prologue + P5b pipelined MFMA; only with EPI)
// Modes launched: 0 (bare skeleton), 1, 3, 7 (full, real output).
// Dummy modes write htH derived from prologue-only red4 -> deterministic.
template<int MODE>
__global__ __launch_bounds__(512, 1) void k_steps_t(
    const float* __restrict__ G2, const float* __restrict__ G3,
    const float* __restrict__ G4it,
    const float* __restrict__ W2, const float* __restrict__ W3,
    const float* __restrict__ W4,
    const float* __restrict__ q_matrix, const int* __restrict__ e_data,
    const float* __restrict__ h0, float* __restrict__ hthist)
{
    __shared__ unsigned short hB[512 * 72];
    __shared__ float2 qP[512];
    __shared__ float htH[100 * 64];
    __shared__ float htS[64], LGs[64], Vs[64];
    __shared__ float red[512], red2[512];
    __shared__ float red4[32 * 68];
    __shared__ int eRow[104];

    const int tid = threadIdx.x;
    const int b   = blockIdx.x;
    const int l   = tid & 63;
    const int w   = tid >> 6;
    const int lm  = l & 15;
    const int lk  = l >> 4;
    const int d   = tid & 63;
    const int kg  = tid >> 6;

    float w2r[8], w3r[8], wbr[8];
    #pragma unroll
    for (int j = 0; j < 8; ++j) {
        w2r[j] = W2[d * 256 + 192 + kg * 8 + j];
        w3r[j] = W3[d * 256 + 192 + kg * 8 + j];
        wbr[j] = W4[d * 192 + 64  + kg * 8 + j];
    }

    short8v afr[4][2];
    #pragma unroll
    for (int dt = 0; dt < 4; ++dt)
        #pragma unroll
        for (int kc = 0; kc < 2; ++kc) {
            const float* src = W4 + (size_t)(dt * 16 + lm) * 192 + kc * 32 + lk * 8;
            union { unsigned short us[8]; short8v v; } u;
            #pragma unroll
            for (int j = 0; j < 8; ++j) u.us[j] = f2bf(src[j]);
            afr[dt][kc] = u.v;
        }

    if (tid < L) eRow[tid] = e_data[b * L + tid];

    f32x4 hreg[4][4];
    #pragma unroll
    for (int st = 0; st < 4; ++st) {
        const int s = (w * 4 + st) * 16 + lm;
        #pragma unroll
        for (int dt = 0; dt < 4; ++dt) {
            const int d0 = dt * 16 + lk * 4;
            f32x4 hv = {0.f, 0.f, 0.f, 0.f};
            if (s < S) hv = *(const f32x4*)(h0 + (size_t)s * 64 + d0);
            hreg[st][dt] = hv;
            *(uint2*)&hB[s * 72 + d0] =
                make_uint2(pack2(hv.x, hv.y), pack2(hv.z, hv.w));
        }
    }

    f32x4 acc[4][4];
    #pragma unroll
    for (int dt = 0; dt < 4; ++dt)
        #pragma unroll
        for (int st = 0; st < 4; ++st) acc[dt][st] = f32x4{0.f, 0.f, 0.f, 0.f};

    if (MODE & 4) {
        short8v bfr[4][2];
        #pragma unroll
        for (int st = 0; st < 4; ++st) {
            const int s = (w * 4 + st) * 16 + lm;
            #pragma unroll
            for (int kc = 0; kc < 2; ++kc)
                bfr[st][kc] = *(const short8v*)&hB[s * 72 + kc * 32 + lk * 8];
        }
        #pragma unroll
        for (int dt = 0; dt < 4; ++dt)
            #pragma unroll
            for (int st = 0; st < 4; ++st) {
                f32x4 z = {0.f, 0.f, 0.f, 0.f};
                z = __builtin_amdgcn_mfma_f32_16x16x32_bf16(afr[dt][0], bfr[st][0], z, 0, 0, 0);
                z = __builtin_amdgcn_mfma_f32_16x16x32_bf16(afr[dt][1], bfr[st][1], z, 0, 0, 0);
                acc[dt][st] = z;
            }
    }
    __syncthreads();

    {
        const float q0 = (tid < S) ? q_matrix[(size_t)eRow[0] * S + tid] : 0.f;
        const float q1 = (tid < S) ? q_matrix[(size_t)eRow[1] * S + tid] : 0.f;
        qP[tid] = make_float2(q0, q1);
    }
    float g2v = 0.f, g3v = 0.f, g4v = 0.f;
    if (tid < 64) {
        g2v = G2[(b * L) * 64 + l];
        g3v = G3[(b * L) * 64 + l];
        g4v = G4it[(b * L) * 64 + l];
    }
    __syncthreads();

    // h_tilde_0 partials (always; stores keep hreg live in all modes)
    {
        f32x4 part[4];
        #pragma unroll
        for (int dt = 0; dt < 4; ++dt) part[dt] = f32x4{0.f, 0.f, 0.f, 0.f};
        #pragma unroll
        for (int st = 0; st < 4; ++st) {
            const int s = (w * 4 + st) * 16 + lm;
            const float qe = qP[s].x;
            #pragma unroll
            for (int dt = 0; dt < 4; ++dt) part[dt] += qe * hreg[st][dt];
        }
        #pragma unroll
        for (int dt = 0; dt < 4; ++dt)
            #pragma unroll
            for (int i = 0; i < 4; ++i) {
                float v = part[dt][i];
                v += __shfl_xor(v, 1); v += __shfl_xor(v, 2);
                part[dt][i] = v;
            }
        if ((lm & 3) == 0) {
            const int g = w * 4 + (lm >> 2);
            #pragma unroll
            for (int dt = 0; dt < 4; ++dt)
                *(f32x4*)&red4[g * 68 + dt * 16 + lk * 4] = part[dt];
        }
    }
    __syncthreads();

    float qn_reg = 0.f;

    for (int t = 0; t < L - 1; ++t) {
        // P6 (wave 0): fold h_tilde_t (always — htH is the live output)
        if (tid < 64) {
            float htd = 0.f;
            #pragma unroll
            for (int g = 0; g < 32; ++g) htd += red4[g * 68 + l];
            htS[l] = htd;
            htH[t * 64 + l] = htd;
        }
        __syncthreads();                           // b6

        // P1: qP shift + q prefetch (always); gate partials (GATES)
        if (t > 0) {
            const float2 qold = qP[tid];
            qP[tid] = make_float2(qold.y, qn_reg);
        }
        {
            const int tn = (t + 2 < L) ? t + 2 : L - 1;
            qn_reg = (tid < S) ? q_matrix[(size_t)eRow[tn] * S + tid] : 0.f;
        }
        if (MODE & 1) {
            const f32x4 h4a = *(const f32x4*)&htS[kg * 8];
            const f32x4 h4b = *(const f32x4*)&htS[kg * 8 + 4];
            float p2 = 0.f, p3 = 0.f;
            #pragma unroll
            for (int j = 0; j < 4; ++j) {
                p2 += w2r[j] * h4a[j] + w2r[4 + j] * h4b[j];
                p3 += w3r[j] * h4a[j] + w3r[4 + j] * h4b[j];
            }
            red[kg * 64 + d]  = p2;
            red2[kg * 64 + d] = p3;
        }
        __syncthreads();                           // b1

        if (MODE & 1) {
            if (tid < 64) {
                float g2 = g2v, g3 = g3v;
                #pragma unroll
                for (int ww = 0; ww < 8; ++ww) { g2 += red[ww * 64 + d]; g3 += red2[ww * 64 + d]; }
                LGs[d] = sigm(g3) * (tanhf(g2) + 1.0f) * 0.5f;
            }
        }
        __syncthreads();                           // b2

        if (MODE & 1) {
            const f32x4 l4a = *(const f32x4*)&LGs[kg * 8];
            const f32x4 l4b = *(const f32x4*)&LGs[kg * 8 + 4];
            float pv = 0.f;
            #pragma unroll
            for (int j = 0; j < 4; ++j)
                pv += wbr[j] * l4a[j] + wbr[4 + j] * l4b[j];
            red[kg * 64 + d] = pv;
        }
        __syncthreads();                           // b3

        if (MODE & 1) {
            if (tid < 64) {
                float v = g4v;
                #pragma unroll
                for (int ww = 0; ww < 8; ++ww) v += red[ww * 64 + d];
                Vs[d] = v;
                g2v = G2[(b * L + t + 1) * 64 + l];
                g3v = G3[(b * L + t + 1) * 64 + l];
                g4v = G4it[(b * L + t + 1) * 64 + l];
            }
        }
        __syncthreads();                           // b4

        if (MODE & 2) {
            float2 qv[4];
            #pragma unroll
            for (int st = 0; st < 4; ++st) qv[st] = qP[(w * 4 + st) * 16 + lm];

            f32x4 part[4];
            #pragma unroll
            for (int dt = 0; dt < 4; ++dt) part[dt] = f32x4{0.f, 0.f, 0.f, 0.f};

            #pragma unroll
            for (int dt = 0; dt < 4; ++dt) {
                const int d0 = dt * 16 + lk * 4;
                const f32x4 lg4 = *(const f32x4*)&LGs[d0];
                const f32x4 v4  = *(const f32x4*)&Vs[d0];
                #pragma unroll
                for (int st = 0; st < 4; ++st) {
                    const int s = (w * 4 + st) * 16 + lm;
                    const float qe = qv[st].x;
                    const float qq = qv[st].y;
                    const f32x4 a  = acc[dt][st];
                    const f32x4 ho = hreg[st][dt];
                    f32x4 hn;
                    hn.x = qe * lg4.x + sigm(a.x + v4.x) * ho.x;
                    hn.y = qe * lg4.y + sigm(a.y + v4.y) * ho.y;
                    hn.z = qe * lg4.z + sigm(a.z + v4.z) * ho.z;
                    hn.w = qe * lg4.w + sigm(a.w + v4.w) * ho.w;
                    hreg[st][dt] = hn;
                    *(uint2*)&hB[s * 72 + d0] =
                        make_uint2(pack2(hn.x, hn.y), pack2(hn.z, hn.w));
                    part[dt] += qq * hn;
                }
            }

            if (MODE & 4) {
                if (t < L - 2) {
                    short8v bfr[4][2];
                    #pragma unroll
                    for (int st = 0; st < 4; ++st) {
                        const int s = (w * 4 + st) * 16 + lm;
                        #pragma unroll
                        for (int kc = 0; kc < 2; ++kc)
                            bfr[st][kc] = *(const short8v*)&hB[s * 72 + kc * 32 + lk * 8];
                    }
                    #pragma unroll
                    for (int dt = 0; dt < 4; ++dt)
                        #pragma unroll
                        for (int st = 0; st < 4; ++st) {
                            f32x4 z = {0.f, 0.f, 0.f, 0.f};
                            z = __builtin_amdgcn_mfma_f32_16x16x32_bf16(afr[dt][0], bfr[st][0], z, 0, 0, 0);
                            z = __builtin_amdgcn_mfma_f32_16x16x32_bf16(afr[dt][1], bfr[st][1], z, 0, 0, 0);
                            acc[dt][st] = z;
                        }
                }
            }

            #pragma unroll
            for (int dt = 0; dt < 4; ++dt)
                #pragma unroll
                for (int i = 0; i < 4; ++i) {
                    float v = part[dt][i];
                    v += __shfl_xor(v, 1); v += __shfl_xor(v, 2);
                    part[dt][i] = v;
                }
            if ((lm & 3) == 0) {
                const int g = w * 4 + (lm >> 2);
                #pragma unroll
                for (int dt = 0; dt < 4; ++dt)
                    *(f32x4*)&red4[g * 68 + dt * 16 + lk * 4] = part[dt];
            }
        }
        __syncthreads();                           // b5
    }

    if (tid < 64) {
        float htd = 0.f;
        #pragma unroll
        for (int g = 0; g < 32; ++g) htd += red4[g * 68 + l];
        htH[99 * 64 + l] = htd;
    }
    __syncthreads();
    for (int i = tid; i < 100 * 64; i += 512)
        hthist[(size_t)(i >> 6) * (B * 64) + b * 64 + (i & 63)] = htH[i];
}

// ---------------- epilogue: y_t for t=1..99 --------------------------------
__global__ __launch_bounds__(64) void k_y(
    const float* __restrict__ hthist, const float* __restrict__ prey,
    const float* __restrict__ W5T, float* __restrict__ pred)
{
    __shared__ float HT[64];
    const int j = blockIdx.x + 1;    // 1..99
    const int b = blockIdx.y;
    const int d = threadIdx.x;
    HT[d] = hthist[(size_t)j * (B * 64) + b * 64 + d];
    __syncthreads();
    float acc = prey[(b * L + j) * 64 + d];
    #pragma unroll 8
    for (int k = 0; k < 64; ++k) acc += W5T[(128 + k) * 64 + d] * HT[k];
    float y = sigm(acc);
    #pragma unroll
    for (int m = 1; m < 64; m <<= 1) y += __shfl_xor(y, m);
    if (d == 0) pred[b * L + j] = y * (1.0f / 64.0f);
}

} // namespace

extern "C" void kernel_launch(void* const* d_in, const int* in_sizes, int n_in,
                              void* d_out, int out_size, void* d_ws, size_t ws_size,
                              hipStream_t stream)
{
    const int*   e_data   = (const int*)d_in[0];
    const int*   a_data   = (const int*)d_in[1];
    const int*   at_data  = (const int*)d_in[2];
    const int*   it_data  = (const int*)d_in[3];
    const float* q_matrix = (const float*)d_in[4];
    const float* h0       = (const float*)d_in[5];
    const float* e_embed  = (const float*)d_in[6];
    const float* at_embed = (const float*)d_in[7];
    const float* it_embed = (const float*)d_in[8];
    const float* W1 = (const float*)d_in[9];  const float* b1 = (const float*)d_in[10];
    const float* W2 = (const float*)d_in[11]; const float* b2 = (const float*)d_in[12];
    const float* W3 = (const float*)d_in[13]; const float* b3 = (const float*)d_in[14];
    const float* W4 = (const float*)d_in[15]; const float* b4 = (const float*)d_in[16];
    const float* W5 = (const float*)d_in[17]; const float* b5 = (const float*)d_in[18];
    float* pred = (float*)d_out;

    float* ws   = (float*)d_ws;
    float* W1T    = ws;                        // 16384
    float* W2T    = W1T    + 16384;            // 16384
    float* W3T    = W2T    + 16384;            // 16384
    float* W4T    = W3T    + 16384;            // 12288
    float* W5T    = W4T    + 12288;            // 12288
    float* allL   = W5T    + 12288;            // 204800
    float* G2     = allL   + 204800;
    float* G3     = G2     + 204800;
    float* G4it   = G3     + 204800;
    float* prey   = G4it   + 204800;
    float* hthist = prey   + 204800;           // L*B*64 = 204800
    float* hdum   = hthist + 204800;           // ablation dummy output

    hipLaunchKernelGGL(k_init, dim3(64), dim3(256), 0, stream,
                       W1, W2, W3, W4, W5, W1T, W2T, W3T, W4T, W5T, pred);
    hipLaunchKernelGGL(k_all_learning, dim3(B * L / 4), dim3(256), 0, stream,
                       e_data, a_data, at_data, e_embed, at_embed, W1T, b1, allL);
    hipLaunchKernelGGL(k_pre, dim3(B * L / 4), dim3(256), 0, stream,
                       e_data, it_data, e_embed, it_embed, allL,
                       W2T, W3T, W4T, W5T, b2, b3, b4, b5, G2, G3, G4it, prey);

    // ---- ablation dispatches (dummy output) — read per-dispatch dur_us ----
    k_steps_t<0><<<dim3(B), dim3(512), 0, stream>>>(
        G2, G3, G4it, W2, W3, W4, q_matrix, e_data, h0, hdum);   // bare skeleton
    k_steps_t<1><<<dim3(B), dim3(512), 0, stream>>>(
        G2, G3, G4it, W2, W3, W4, q_matrix, e_data, h0, hdum);   // + gates
    k_steps_t<3><<<dim3(B), dim3(512), 0, stream>>>(
        G2, G3, G4it, W2, W3, W4, q_matrix, e_data, h0, hdum);   // + epilogue

    // ---- real run (full) ----
    k_steps_t<7><<<dim3(B), dim3(512), 0, stream>>>(
        G2, G3, G4it, W2, W3, W4, q_matrix, e_data, h0, hthist);

    hipLaunchKernelGGL(k_y, dim3(L - 1, B), dim3(64), 0, stream,
                       hthist, prey, W5T, pred);
}

// Round 15
// 1009.917 us; speedup vs baseline: 1.1367x; 1.1367x over previous
//
#include <hip/hip_runtime.h>
#include <hip/hip_bf16.h>

namespace {

constexpr int B  = 32;
constexpr int L  = 100;
constexpr int S  = 501;
constexpr int DK = 64;
constexpr int DE = 128;

typedef __attribute__((ext_vector_type(8))) short short8v;   // 8 bf16 (4 VGPR)
typedef __attribute__((ext_vector_type(4))) float f32x4;
typedef unsigned int u32;

__device__ __forceinline__ float sigm(float x) {
    return __fdividef(1.0f, 1.0f + __expf(-x));
}
// fp32 -> bf16 RNE (one-time staging only)
__device__ __forceinline__ unsigned short f2bf(float f) {
    u32 u = __float_as_uint(f);
    u += 0x7FFFu + ((u >> 16) & 1u);
    return (unsigned short)(u >> 16);
}
// pack two fp32 -> u32 of 2 bf16, round-half-up (4 ops; hot path)
__device__ __forceinline__ u32 pack2(float a, float b) {
    const u32 ua = __float_as_uint(a) + 0x8000u;
    const u32 ub = __float_as_uint(b) + 0x8000u;
    return (ua >> 16) | (ub & 0xFFFF0000u);
}

// ---------------- init: transpose weights (k-major) for pre/y, pred[:,0] ---
__global__ __launch_bounds__(256) void k_init(
    const float* __restrict__ W1, const float* __restrict__ W2,
    const float* __restrict__ W3, const float* __restrict__ W4,
    const float* __restrict__ W5,
    float* __restrict__ W1T, float* __restrict__ W2T, float* __restrict__ W3T,
    float* __restrict__ W4T, float* __restrict__ W5T,
    float* __restrict__ pred)
{
    const int idx = blockIdx.x * 256 + threadIdx.x;
    const int st  = gridDim.x * 256;
    for (int i = idx; i < 64 * 256; i += st) {
        int dd = i >> 8, kk = i & 255;
        W1T[kk * 64 + dd] = W1[i];
        W2T[kk * 64 + dd] = W2[i];
        W3T[kk * 64 + dd] = W3[i];
    }
    for (int i = idx; i < 64 * 192; i += st) {
        int dd = i / 192, kk = i % 192;
        W4T[kk * 64 + dd] = W4[i];
        W5T[kk * 64 + dd] = W5[i];
    }
    if (idx < B) pred[idx * L] = 0.0f;
}

// ---------------- all_learning = concat(e,at,a) @ W1^T + b1 ----------------
__global__ __launch_bounds__(256) void k_all_learning(
    const int* __restrict__ e_data, const int* __restrict__ a_data,
    const int* __restrict__ at_data,
    const float* __restrict__ e_embed, const float* __restrict__ at_embed,
    const float* __restrict__ W1T, const float* __restrict__ b1,
    float* __restrict__ allL)
{
    __shared__ float in_s[4][257];
    const int g = threadIdx.x >> 6;
    const int d = threadIdx.x & 63;
    const int row = blockIdx.x * 4 + g;
    const int e  = e_data[row];
    const int at = at_data[row];
    in_s[g][d]       = e_embed[(size_t)e * DE + d];
    in_s[g][64 + d]  = e_embed[(size_t)e * DE + 64 + d];
    in_s[g][128 + d] = at_embed[(size_t)at * DK + d];
    in_s[g][192 + d] = (float)a_data[row];
    __syncthreads();
    float acc = b1[d];
    #pragma unroll 8
    for (int k = 0; k < 256; ++k) acc += W1T[k * 64 + d] * in_s[g][k];
    allL[row * DK + d] = acc;
}

// ---------------- G2,G3 (non-recurrent parts), G4it, prey ------------------
__global__ __launch_bounds__(256) void k_pre(
    const int* __restrict__ e_data, const int* __restrict__ it_data,
    const float* __restrict__ e_embed, const float* __restrict__ it_embed,
    const float* __restrict__ allL,
    const float* __restrict__ W2T, const float* __restrict__ W3T,
    const float* __restrict__ W4T, const float* __restrict__ W5T,
    const float* __restrict__ b2, const float* __restrict__ b3,
    const float* __restrict__ b4, const float* __restrict__ b5,
    float* __restrict__ G2, float* __restrict__ G3,
    float* __restrict__ G4it, float* __restrict__ prey)
{
    __shared__ float lp[4][64], its[4][64], ln[4][64], ee[4][128];
    const int g = threadIdx.x >> 6;
    const int d = threadIdx.x & 63;
    const int row = blockIdx.x * 4 + g;
    const int t = row % L;
    lp[g][d]  = (t == 0) ? 0.0f : allL[(row - 1) * 64 + d];
    its[g][d] = it_embed[(size_t)it_data[row] * 64 + d];
    ln[g][d]  = allL[row * 64 + d];
    const int e = e_data[row];
    ee[g][d]      = e_embed[(size_t)e * DE + d];
    ee[g][64 + d] = e_embed[(size_t)e * DE + 64 + d];
    __syncthreads();
    float g2 = b2[d], g3 = b3[d], g4 = b4[d], py = b5[d];
    #pragma unroll 4
    for (int k = 0; k < 64; ++k) {
        const float l0 = lp[g][k], i0 = its[g][k], n0 = ln[g][k];
        g2 += W2T[k * 64 + d] * l0 + W2T[(64 + k) * 64 + d] * i0 + W2T[(128 + k) * 64 + d] * n0;
        g3 += W3T[k * 64 + d] * l0 + W3T[(64 + k) * 64 + d] * i0 + W3T[(128 + k) * 64 + d] * n0;
        g4 += W4T[(128 + k) * 64 + d] * i0;
        py += W5T[k * 64 + d] * ee[g][k] + W5T[(64 + k) * 64 + d] * ee[g][64 + k];
    }
    G2[row * 64 + d]   = g2;
    G3[row * 64 + d]   = g3;
    G4it[row * 64 + d] = g4;
    prey[row * 64 + d] = py;
}

// ---------------- persistent recurrence: one block per BATCH ---------------
// NEW vs r13: 1024 threads (16 waves = 4 waves/SIMD, 2x issue-slot fill).
// Each wave owns 32 s-rows (st=0..1); k-split for gate dots is 16-way (4 k
// per group). Same 6-barrier phasing, pipelined MFMA, padded red4.
__global__ __launch_bounds__(1024, 1) void k_steps(
    const float* __restrict__ G2, const float* __restrict__ G3,
    const float* __restrict__ G4it,
    const float* __restrict__ W2, const float* __restrict__ W3,
    const float* __restrict__ W4,
    const float* __restrict__ q_matrix, const int* __restrict__ e_data,
    const float* __restrict__ h0, float* __restrict__ hthist)
{
    __shared__ unsigned short hB[512 * 72];   // h mirror bf16 (73728 B)
    __shared__ float2 qP[512];                // {q[e_t], q[e_{t+1}]} (4096 B)
    __shared__ float htH[100 * 64];           // h_tilde history (25600 B)
    __shared__ float htS[64], LGs[64], Vs[64];
    __shared__ float red[16 * 64], red2[16 * 64];  // gate partials (8192 B)
    __shared__ float red4[32 * 68];           // h_tilde partials, padded (8704 B)
    __shared__ int eRow[104];                 // ~121 KB total

    const int tid = threadIdx.x;
    const int b   = blockIdx.x;
    const int l   = tid & 63;     // lane
    const int w   = tid >> 6;     // wave 0..15
    const int lm  = l & 15;
    const int lk  = l >> 4;
    const int d   = l;            // gate-phase d index
    const int kg  = w;            // gate-phase k group 0..15 (4 k each)

    // ---- per-thread gate weight registers (4-wide slices) ----
    float w2r[4], w3r[4], wbr[4];
    #pragma unroll
    for (int j = 0; j < 4; ++j) {
        w2r[j] = W2[d * 256 + 192 + kg * 4 + j];
        w3r[j] = W3[d * 256 + 192 + kg * 4 + j];
        wbr[j] = W4[d * 192 + 64  + kg * 4 + j];
    }

    // ---- A-fragments: W4a[d][k] bf16, persistent in regs ----
    short8v afr[4][2];
    #pragma unroll
    for (int dt = 0; dt < 4; ++dt)
        #pragma unroll
        for (int kc = 0; kc < 2; ++kc) {
            const float* src = W4 + (size_t)(dt * 16 + lm) * 192 + kc * 32 + lk * 8;
            union { unsigned short us[8]; short8v v; } u;
            #pragma unroll
            for (int j = 0; j < 8; ++j) u.us[j] = f2bf(src[j]);
            afr[dt][kc] = u.v;
        }

    if (tid < L) eRow[tid] = e_data[b * L + tid];

    // ---- h registers + bf16 LDS mirror (each wave owns 32 rows) ----
    f32x4 hreg[2][4];   // [st][dt]: h[s][d0..3], s=(w*2+st)*16+lm, d0=dt*16+lk*4
    #pragma unroll
    for (int st = 0; st < 2; ++st) {
        const int s = (w * 2 + st) * 16 + lm;
        #pragma unroll
        for (int dt = 0; dt < 4; ++dt) {
            const int d0 = dt * 16 + lk * 4;
            f32x4 hv = {0.f, 0.f, 0.f, 0.f};
            if (s < S) hv = *(const f32x4*)(h0 + (size_t)s * 64 + d0);
            hreg[st][dt] = hv;
            *(uint2*)&hB[s * 72 + d0] =
                make_uint2(pack2(hv.x, hv.y), pack2(hv.z, hv.w));
        }
    }

    // ---- MFMA for t=0 (wave-private hB rows; same-wave RAW is ordered) ----
    f32x4 acc[4][2];
    {
        short8v bfr[2][2];
        #pragma unroll
        for (int st = 0; st < 2; ++st) {
            const int s = (w * 2 + st) * 16 + lm;
            #pragma unroll
            for (int kc = 0; kc < 2; ++kc)
                bfr[st][kc] = *(const short8v*)&hB[s * 72 + kc * 32 + lk * 8];
        }
        #pragma unroll
        for (int dt = 0; dt < 4; ++dt)
            #pragma unroll
            for (int st = 0; st < 2; ++st) {
                f32x4 z = {0.f, 0.f, 0.f, 0.f};
                z = __builtin_amdgcn_mfma_f32_16x16x32_bf16(afr[dt][0], bfr[st][0], z, 0, 0, 0);
                z = __builtin_amdgcn_mfma_f32_16x16x32_bf16(afr[dt][1], bfr[st][1], z, 0, 0, 0);
                acc[dt][st] = z;
            }
    }
    __syncthreads();                               // eRow/hB ready

    // ---- prologue: qP = {q[e0], q[e1]}; prefetch G[t=0] ----
    if (tid < 512) {
        const float q0 = (tid < S) ? q_matrix[(size_t)eRow[0] * S + tid] : 0.f;
        const float q1 = (tid < S) ? q_matrix[(size_t)eRow[1] * S + tid] : 0.f;
        qP[tid] = make_float2(q0, q1);
    }
    float g2v = 0.f, g3v = 0.f, g4v = 0.f;
    if (tid < 64) {
        g2v = G2[(b * L) * 64 + l];
        g3v = G3[(b * L) * 64 + l];
        g4v = G4it[(b * L) * 64 + l];
    }
    __syncthreads();                               // qP ready

    // ---- h_tilde_0 partials (3-round shfl -> red4; 2 writer lanes/wave) ----
    {
        f32x4 part[4];
        #pragma unroll
        for (int dt = 0; dt < 4; ++dt) part[dt] = f32x4{0.f, 0.f, 0.f, 0.f};
        #pragma unroll
        for (int st = 0; st < 2; ++st) {
            const int s = (w * 2 + st) * 16 + lm;
            const float qe = qP[s].x;
            #pragma unroll
            for (int dt = 0; dt < 4; ++dt) part[dt] += qe * hreg[st][dt];
        }
        #pragma unroll
        for (int dt = 0; dt < 4; ++dt)
            #pragma unroll
            for (int i = 0; i < 4; ++i) {
                float v = part[dt][i];
                v += __shfl_xor(v, 1); v += __shfl_xor(v, 2); v += __shfl_xor(v, 4);
                part[dt][i] = v;
            }
        if ((lm & 7) == 0) {
            const int g = w * 2 + (lm >> 3);
            #pragma unroll
            for (int dt = 0; dt < 4; ++dt)
                *(f32x4*)&red4[g * 68 + dt * 16 + lk * 4] = part[dt];
        }
    }
    __syncthreads();                               // red4 ready (acts as b5)

    float qn_reg = 0.f;   // q[e_{t+2}] row element (threads <512)

    // ---------------- 99 steps ----------------
    for (int t = 0; t < L - 1; ++t) {
        // P6 (wave 0): fold h_tilde_t -> htS, htH
        if (tid < 64) {
            float htd = 0.f;
            #pragma unroll
            for (int g = 0; g < 32; ++g) htd += red4[g * 68 + l];
            htS[l] = htd;
            htH[t * 64 + l] = htd;
        }
        __syncthreads();                           // b6

        // P1: qP shift + q prefetch (threads<512); gate partials (all)
        if (tid < 512) {
            if (t > 0) {
                const float2 qold = qP[tid];
                qP[tid] = make_float2(qold.y, qn_reg);
            }
            const int tn = (t + 2 < L) ? t + 2 : L - 1;
            qn_reg = (tid < S) ? q_matrix[(size_t)eRow[tn] * S + tid] : 0.f;
        }
        {
            const f32x4 h4 = *(const f32x4*)&htS[kg * 4];
            float p2 = 0.f, p3 = 0.f;
            #pragma unroll
            for (int j = 0; j < 4; ++j) {
                p2 += w2r[j] * h4[j];
                p3 += w3r[j] * h4[j];
            }
            red[kg * 64 + d]  = p2;
            red2[kg * 64 + d] = p3;
        }
        __syncthreads();                           // b1

        // P2 (wave 0): LG
        if (tid < 64) {
            float g2 = g2v, g3 = g3v;
            #pragma unroll
            for (int ww = 0; ww < 16; ++ww) { g2 += red[ww * 64 + d]; g3 += red2[ww * 64 + d]; }
            LGs[d] = sigm(g3) * (tanhf(g2) + 1.0f) * 0.5f;
        }
        __syncthreads();                           // b2

        // P3 (all): W4b @ LG partials
        {
            const f32x4 l4 = *(const f32x4*)&LGs[kg * 4];
            float pv = 0.f;
            #pragma unroll
            for (int j = 0; j < 4; ++j) pv += wbr[j] * l4[j];
            red[kg * 64 + d] = pv;
        }
        __syncthreads();                           // b3

        // P4 (wave 0): Vs fold + G prefetch for next step
        if (tid < 64) {
            float v = g4v;
            #pragma unroll
            for (int ww = 0; ww < 16; ++ww) v += red[ww * 64 + d];
            Vs[d] = v;
            g2v = G2[(b * L + t + 1) * 64 + l];
            g3v = G3[(b * L + t + 1) * 64 + l];
            g4v = G4it[(b * L + t + 1) * 64 + l];
        }
        __syncthreads();                           // b4

        // P5: epilogue (acc precomputed) -> h update, hB writes, partials
        float2 qv[2];
        #pragma unroll
        for (int st = 0; st < 2; ++st) qv[st] = qP[(w * 2 + st) * 16 + lm];

        f32x4 part[4];
        #pragma unroll
        for (int dt = 0; dt < 4; ++dt) part[dt] = f32x4{0.f, 0.f, 0.f, 0.f};

        #pragma unroll
        for (int dt = 0; dt < 4; ++dt) {
            const int d0 = dt * 16 + lk * 4;
            const f32x4 lg4 = *(const f32x4*)&LGs[d0];
            const f32x4 v4  = *(const f32x4*)&Vs[d0];
            #pragma unroll
            for (int st = 0; st < 2; ++st) {
                const int s = (w * 2 + st) * 16 + lm;
                const float qe = qv[st].x;
                const float qq = qv[st].y;
                const f32x4 a  = acc[dt][st];
                const f32x4 ho = hreg[st][dt];
                f32x4 hn;
                hn.x = qe * lg4.x + sigm(a.x + v4.x) * ho.x;
                hn.y = qe * lg4.y + sigm(a.y + v4.y) * ho.y;
                hn.z = qe * lg4.z + sigm(a.z + v4.z) * ho.z;
                hn.w = qe * lg4.w + sigm(a.w + v4.w) * ho.w;
                hreg[st][dt] = hn;
                *(uint2*)&hB[s * 72 + d0] =
                    make_uint2(pack2(hn.x, hn.y), pack2(hn.z, hn.w));
                part[dt] += qq * hn;
            }
        }

        // P5b: next step's MFMA (wave-private hB, no barrier needed)
        if (t < L - 2) {
            short8v bfr[2][2];
            #pragma unroll
            for (int st = 0; st < 2; ++st) {
                const int s = (w * 2 + st) * 16 + lm;
                #pragma unroll
                for (int kc = 0; kc < 2; ++kc)
                    bfr[st][kc] = *(const short8v*)&hB[s * 72 + kc * 32 + lk * 8];
            }
            #pragma unroll
            for (int dt = 0; dt < 4; ++dt)
                #pragma unroll
                for (int st = 0; st < 2; ++st) {
                    f32x4 z = {0.f, 0.f, 0.f, 0.f};
                    z = __builtin_amdgcn_mfma_f32_16x16x32_bf16(afr[dt][0], bfr[st][0], z, 0, 0, 0);
                    z = __builtin_amdgcn_mfma_f32_16x16x32_bf16(afr[dt][1], bfr[st][1], z, 0, 0, 0);
                    acc[dt][st] = z;
                }
        }

        // h_tilde_{t+1} partials: 3-round shfl, 2 writer lanes/wave -> red4
        #pragma unroll
        for (int dt = 0; dt < 4; ++dt)
            #pragma unroll
            for (int i = 0; i < 4; ++i) {
                float v = part[dt][i];
                v += __shfl_xor(v, 1); v += __shfl_xor(v, 2); v += __shfl_xor(v, 4);
                part[dt][i] = v;
            }
        if ((lm & 7) == 0) {
            const int g = w * 2 + (lm >> 3);
            #pragma unroll
            for (int dt = 0; dt < 4; ++dt)
                *(f32x4*)&red4[g * 68 + dt * 16 + lk * 4] = part[dt];
        }
        __syncthreads();                           // b5
    }

    // final fold: h_tilde_99 -> htH[99]
    if (tid < 64) {
        float htd = 0.f;
        #pragma unroll
        for (int g = 0; g < 32; ++g) htd += red4[g * 68 + l];
        htH[99 * 64 + l] = htd;
    }
    __syncthreads();
    // bulk write h_tilde history to global (coalesced)
    for (int i = tid; i < 100 * 64; i += 1024)
        hthist[(size_t)(i >> 6) * (B * 64) + b * 64 + (i & 63)] = htH[i];
}

// ---------------- epilogue: y_t for t=1..99 --------------------------------
__global__ __launch_bounds__(64) void k_y(
    const float* __restrict__ hthist, const float* __restrict__ prey,
    const float* __restrict__ W5T, float* __restrict__ pred)
{
    __shared__ float HT[64];
    const int j = blockIdx.x + 1;    // 1..99
    const int b = blockIdx.y;
    const int d = threadIdx.x;
    HT[d] = hthist[(size_t)j * (B * 64) + b * 64 + d];
    __syncthreads();
    float acc = prey[(b * L + j) * 64 + d];
    #pragma unroll 8
    for (int k = 0; k < 64; ++k) acc += W5T[(128 + k) * 64 + d] * HT[k];
    float y = sigm(acc);
    #pragma unroll
    for (int m = 1; m < 64; m <<= 1) y += __shfl_xor(y, m);
    if (d == 0) pred[b * L + j] = y * (1.0f / 64.0f);
}

} // namespace

extern "C" void kernel_launch(void* const* d_in, const int* in_sizes, int n_in,
                              void* d_out, int out_size, void* d_ws, size_t ws_size,
                              hipStream_t stream)
{
    const int*   e_data   = (const int*)d_in[0];
    const int*   a_data   = (const int*)d_in[1];
    const int*   at_data  = (const int*)d_in[2];
    const int*   it_data  = (const int*)d_in[3];
    const float* q_matrix = (const float*)d_in[4];
    const float* h0       = (const float*)d_in[5];
    const float* e_embed  = (const float*)d_in[6];
    const float* at_embed = (const float*)d_in[7];
    const float* it_embed = (const float*)d_in[8];
    const float* W1 = (const float*)d_in[9];  const float* b1 = (const float*)d_in[10];
    const float* W2 = (const float*)d_in[11]; const float* b2 = (const float*)d_in[12];
    const float* W3 = (const float*)d_in[13]; const float* b3 = (const float*)d_in[14];
    const float* W4 = (const float*)d_in[15]; const float* b4 = (const float*)d_in[16];
    const float* W5 = (const float*)d_in[17]; const float* b5 = (const float*)d_in[18];
    float* pred = (float*)d_out;

    float* ws   = (float*)d_ws;
    float* W1T    = ws;                        // 16384
    float* W2T    = W1T    + 16384;            // 16384
    float* W3T    = W2T    + 16384;            // 16384
    float* W4T    = W3T    + 16384;            // 12288
    float* W5T    = W4T    + 12288;            // 12288
    float* allL   = W5T    + 12288;            // 204800
    float* G2     = allL   + 204800;
    float* G3     = G2     + 204800;
    float* G4it   = G3     + 204800;
    float* prey   = G4it   + 204800;
    float* hthist = prey   + 204800;           // L*B*64 = 204800
    // total ~5.2 MB

    hipLaunchKernelGGL(k_init, dim3(64), dim3(256), 0, stream,
                       W1, W2, W3, W4, W5, W1T, W2T, W3T, W4T, W5T, pred);
    hipLaunchKernelGGL(k_all_learning, dim3(B * L / 4), dim3(256), 0, stream,
                       e_data, a_data, at_data, e_embed, at_embed, W1T, b1, allL);
    hipLaunchKernelGGL(k_pre, dim3(B * L / 4), dim3(256), 0, stream,
                       e_data, it_data, e_embed, it_embed, allL,
                       W2T, W3T, W4T, W5T, b2, b3, b4, b5, G2, G3, G4it, prey);
    hipLaunchKernelGGL(k_steps, dim3(B), dim3(1024), 0, stream,
                       G2, G3, G4it, W2, W3, W4, q_matrix, e_data, h0, hthist);
    hipLaunchKernelGGL(k_y, dim3(L - 1, B), dim3(64), 0, stream,
                       hthist, prey, W5T, pred);
}

// Round 16
// 785.746 us; speedup vs baseline: 1.4609x; 1.2853x over previous
//
#include <hip/hip_runtime.h>
#include <hip/hip_bf16.h>

namespace {

constexpr int B  = 32;
constexpr int L  = 100;
constexpr int S  = 501;
constexpr int DK = 64;
constexpr int DE = 128;

typedef __attribute__((ext_vector_type(8))) short short8v;   // 8 bf16 (4 VGPR)
typedef __attribute__((ext_vector_type(4))) float f32x4;
typedef unsigned int u32;

__device__ __forceinline__ float sigm(float x) {
    return __fdividef(1.0f, 1.0f + __expf(-x));
}
// fp32 -> bf16 RNE (one-time staging only)
__device__ __forceinline__ unsigned short f2bf(float f) {
    u32 u = __float_as_uint(f);
    u += 0x7FFFu + ((u >> 16) & 1u);
    return (unsigned short)(u >> 16);
}
// pack two fp32 -> u32 of 2 bf16, round-half-up (4 ops; hot path)
__device__ __forceinline__ u32 pack2(float a, float b) {
    const u32 ua = __float_as_uint(a) + 0x8000u;
    const u32 ub = __float_as_uint(b) + 0x8000u;
    return (ua >> 16) | (ub & 0xFFFF0000u);
}

// ---------------- init: transpose weights (k-major) for pre/y, pred[:,0] ---
__global__ __launch_bounds__(256) void k_init(
    const float* __restrict__ W1, const float* __restrict__ W2,
    const float* __restrict__ W3, const float* __restrict__ W4,
    const float* __restrict__ W5,
    float* __restrict__ W1T, float* __restrict__ W2T, float* __restrict__ W3T,
    float* __restrict__ W4T, float* __restrict__ W5T,
    float* __restrict__ pred)
{
    const int idx = blockIdx.x * 256 + threadIdx.x;
    const int st  = gridDim.x * 256;
    for (int i = idx; i < 64 * 256; i += st) {
        int dd = i >> 8, kk = i & 255;
        W1T[kk * 64 + dd] = W1[i];
        W2T[kk * 64 + dd] = W2[i];
        W3T[kk * 64 + dd] = W3[i];
    }
    for (int i = idx; i < 64 * 192; i += st) {
        int dd = i / 192, kk = i % 192;
        W4T[kk * 64 + dd] = W4[i];
        W5T[kk * 64 + dd] = W5[i];
    }
    if (idx < B) pred[idx * L] = 0.0f;
}

// ---------------- all_learning = concat(e,at,a) @ W1^T + b1 ----------------
__global__ __launch_bounds__(256) void k_all_learning(
    const int* __restrict__ e_data, const int* __restrict__ a_data,
    const int* __restrict__ at_data,
    const float* __restrict__ e_embed, const float* __restrict__ at_embed,
    const float* __restrict__ W1T, const float* __restrict__ b1,
    float* __restrict__ allL)
{
    __shared__ float in_s[4][257];
    const int g = threadIdx.x >> 6;
    const int d = threadIdx.x & 63;
    const int row = blockIdx.x * 4 + g;
    const int e  = e_data[row];
    const int at = at_data[row];
    in_s[g][d]       = e_embed[(size_t)e * DE + d];
    in_s[g][64 + d]  = e_embed[(size_t)e * DE + 64 + d];
    in_s[g][128 + d] = at_embed[(size_t)at * DK + d];
    in_s[g][192 + d] = (float)a_data[row];
    __syncthreads();
    float acc = b1[d];
    #pragma unroll 8
    for (int k = 0; k < 256; ++k) acc += W1T[k * 64 + d] * in_s[g][k];
    allL[row * DK + d] = acc;
}

// ---------------- G2,G3 (non-recurrent parts), G4it, prey ------------------
__global__ __launch_bounds__(256) void k_pre(
    const int* __restrict__ e_data, const int* __restrict__ it_data,
    const float* __restrict__ e_embed, const float* __restrict__ it_embed,
    const float* __restrict__ allL,
    const float* __restrict__ W2T, const float* __restrict__ W3T,
    const float* __restrict__ W4T, const float* __restrict__ W5T,
    const float* __restrict__ b2, const float* __restrict__ b3,
    const float* __restrict__ b4, const float* __restrict__ b5,
    float* __restrict__ G2, float* __restrict__ G3,
    float* __restrict__ G4it, float* __restrict__ prey)
{
    __shared__ float lp[4][64], its[4][64], ln[4][64], ee[4][128];
    const int g = threadIdx.x >> 6;
    const int d = threadIdx.x & 63;
    const int row = blockIdx.x * 4 + g;
    const int t = row % L;
    lp[g][d]  = (t == 0) ? 0.0f : allL[(row - 1) * 64 + d];
    its[g][d] = it_embed[(size_t)it_data[row] * 64 + d];
    ln[g][d]  = allL[row * 64 + d];
    const int e = e_data[row];
    ee[g][d]      = e_embed[(size_t)e * DE + d];
    ee[g][64 + d] = e_embed[(size_t)e * DE + 64 + d];
    __syncthreads();
    float g2 = b2[d], g3 = b3[d], g4 = b4[d], py = b5[d];
    #pragma unroll 4
    for (int k = 0; k < 64; ++k) {
        const float l0 = lp[g][k], i0 = its[g][k], n0 = ln[g][k];
        g2 += W2T[k * 64 + d] * l0 + W2T[(64 + k) * 64 + d] * i0 + W2T[(128 + k) * 64 + d] * n0;
        g3 += W3T[k * 64 + d] * l0 + W3T[(64 + k) * 64 + d] * i0 + W3T[(128 + k) * 64 + d] * n0;
        g4 += W4T[(128 + k) * 64 + d] * i0;
        py += W5T[k * 64 + d] * ee[g][k] + W5T[(64 + k) * 64 + d] * ee[g][64 + k];
    }
    G2[row * 64 + d]   = g2;
    G3[row * 64 + d]   = g3;
    G4it[row * 64 + d] = g4;
    prey[row * 64 + d] = py;
}

// ---------------- persistent recurrence: one block per BATCH ---------------
// 32 blocks x 512 threads (8 waves). NEW vs r13: THREE barriers/step, zero
// wave-0-serial phases. All waves fold red4/red23/red redundantly (LDS
// broadcast reads); h_tilde, LG, V live in registers (lane l owns index l);
// cross-lane values for gate dots and epilogue come from __shfl.
__global__ __launch_bounds__(512, 1) void k_steps(
    const float* __restrict__ G2, const float* __restrict__ G3,
    const float* __restrict__ G4it,
    const float* __restrict__ W2, const float* __restrict__ W3,
    const float* __restrict__ W4,
    const float* __restrict__ q_matrix, const int* __restrict__ e_data,
    const float* __restrict__ h0, float* __restrict__ hthist)
{
    __shared__ unsigned short hB[512 * 72];   // h mirror bf16 (73728 B)
    __shared__ float2 qP[512];                // {q[e_t], q[e_{t+1}]} (4096 B)
    __shared__ float htH[100 * 64];           // h_tilde history (25600 B)
    __shared__ float2 red23[8 * 64];          // {p2,p3} gate partials (4096 B)
    __shared__ float red[8 * 64];             // pv partials (2048 B)
    __shared__ float red4[32 * 68];           // h_tilde partials, padded (8704 B)
    __shared__ int eRow[104];                 // ~119 KB total

    const int tid = threadIdx.x;
    const int b   = blockIdx.x;
    const int l   = tid & 63;     // lane (also the d/k index this lane owns)
    const int w   = tid >> 6;     // wave 0..7 (also gate k-group)
    const int lm  = l & 15;
    const int lk  = l >> 4;

    // ---- per-thread gate weight registers (8-wide slices, row d=l, k grp w)
    float w2r[8], w3r[8], wbr[8];
    #pragma unroll
    for (int j = 0; j < 8; ++j) {
        w2r[j] = W2[l * 256 + 192 + w * 8 + j];
        w3r[j] = W3[l * 256 + 192 + w * 8 + j];
        wbr[j] = W4[l * 192 + 64  + w * 8 + j];
    }

    // ---- A-fragments: W4a[d][k] bf16, persistent in regs ----
    short8v afr[4][2];
    #pragma unroll
    for (int dt = 0; dt < 4; ++dt)
        #pragma unroll
        for (int kc = 0; kc < 2; ++kc) {
            const float* src = W4 + (size_t)(dt * 16 + lm) * 192 + kc * 32 + lk * 8;
            union { unsigned short us[8]; short8v v; } u;
            #pragma unroll
            for (int j = 0; j < 8; ++j) u.us[j] = f2bf(src[j]);
            afr[dt][kc] = u.v;
        }

    if (tid < L) eRow[tid] = e_data[b * L + tid];

    // ---- h registers + bf16 LDS mirror ----
    f32x4 hreg[4][4];   // [st][dt]: h[s][d0..3], s=(w*4+st)*16+lm, d0=dt*16+lk*4
    #pragma unroll
    for (int st = 0; st < 4; ++st) {
        const int s = (w * 4 + st) * 16 + lm;
        #pragma unroll
        for (int dt = 0; dt < 4; ++dt) {
            const int d0 = dt * 16 + lk * 4;
            f32x4 hv = {0.f, 0.f, 0.f, 0.f};
            if (s < S) hv = *(const f32x4*)(h0 + (size_t)s * 64 + d0);
            hreg[st][dt] = hv;
            *(uint2*)&hB[s * 72 + d0] =
                make_uint2(pack2(hv.x, hv.y), pack2(hv.z, hv.w));
        }
    }

    // ---- MFMA for t=0 (wave-private hB rows; same-wave RAW is ordered) ----
    f32x4 acc[4][4];
    {
        short8v bfr[4][2];
        #pragma unroll
        for (int st = 0; st < 4; ++st) {
            const int s = (w * 4 + st) * 16 + lm;
            #pragma unroll
            for (int kc = 0; kc < 2; ++kc)
                bfr[st][kc] = *(const short8v*)&hB[s * 72 + kc * 32 + lk * 8];
        }
        #pragma unroll
        for (int dt = 0; dt < 4; ++dt)
            #pragma unroll
            for (int st = 0; st < 4; ++st) {
                f32x4 z = {0.f, 0.f, 0.f, 0.f};
                z = __builtin_amdgcn_mfma_f32_16x16x32_bf16(afr[dt][0], bfr[st][0], z, 0, 0, 0);
                z = __builtin_amdgcn_mfma_f32_16x16x32_bf16(afr[dt][1], bfr[st][1], z, 0, 0, 0);
                acc[dt][st] = z;
            }
    }
    __syncthreads();                               // eRow/hB ready

    // ---- prologue: qP = {q[e0], q[e1]}; G[t=0] for ALL threads (lane l) ---
    {
        const float q0 = (tid < S) ? q_matrix[(size_t)eRow[0] * S + tid] : 0.f;
        const float q1 = (tid < S) ? q_matrix[(size_t)eRow[1] * S + tid] : 0.f;
        qP[tid] = make_float2(q0, q1);
    }
    float g2v = G2[(b * L) * 64 + l];
    float g3v = G3[(b * L) * 64 + l];
    float g4v = G4it[(b * L) * 64 + l];
    __syncthreads();                               // qP ready

    // ---- h_tilde_0 partials (2-round shfl -> red4) ----
    {
        f32x4 part[4];
        #pragma unroll
        for (int dt = 0; dt < 4; ++dt) part[dt] = f32x4{0.f, 0.f, 0.f, 0.f};
        #pragma unroll
        for (int st = 0; st < 4; ++st) {
            const int s = (w * 4 + st) * 16 + lm;
            const float qe = qP[s].x;
            #pragma unroll
            for (int dt = 0; dt < 4; ++dt) part[dt] += qe * hreg[st][dt];
        }
        #pragma unroll
        for (int dt = 0; dt < 4; ++dt)
            #pragma unroll
            for (int i = 0; i < 4; ++i) {
                float v = part[dt][i];
                v += __shfl_xor(v, 1); v += __shfl_xor(v, 2);
                part[dt][i] = v;
            }
        if ((lm & 3) == 0) {
            const int g = w * 4 + (lm >> 2);
            #pragma unroll
            for (int dt = 0; dt < 4; ++dt)
                *(f32x4*)&red4[g * 68 + dt * 16 + lk * 4] = part[dt];
        }
    }
    __syncthreads();                               // red4 ready (acts as B3)

    float qn_reg = 0.f;   // q[e_{t+2}] row element (loaded in-loop)

    // ---------------- 99 steps, 3 barriers each ----------------
    for (int t = 0; t < L - 1; ++t) {
        // ---- A: all-wave fold of h_tilde_t; gate partials via shfl ----
        float htd = 0.f;
        #pragma unroll
        for (int g = 0; g < 32; ++g) htd += red4[g * 68 + l];
        if (w == 0) htH[t * 64 + l] = htd;         // history (read at end only)

        if (t > 0) {
            const float2 qold = qP[tid];
            qP[tid] = make_float2(qold.y, qn_reg);
        }
        {
            const int tn = (t + 2 < L) ? t + 2 : L - 1;
            qn_reg = (tid < S) ? q_matrix[(size_t)eRow[tn] * S + tid] : 0.f;
        }
        {
            float p2 = 0.f, p3 = 0.f;
            #pragma unroll
            for (int j = 0; j < 8; ++j) {
                const float hv = __shfl(htd, w * 8 + j);
                p2 += w2r[j] * hv;
                p3 += w3r[j] * hv;
            }
            red23[w * 64 + l] = make_float2(p2, p3);
        }
        __syncthreads();                           // B1

        // ---- B: all-wave LG; pv partials via shfl ----
        float g2 = g2v, g3 = g3v;
        #pragma unroll
        for (int ww = 0; ww < 8; ++ww) {
            const float2 r = red23[ww * 64 + l];
            g2 += r.x; g3 += r.y;
        }
        const float LGr = sigm(g3) * (tanhf(g2) + 1.0f) * 0.5f;   // LG[d=l]
        {
            float pv = 0.f;
            #pragma unroll
            for (int j = 0; j < 8; ++j) pv += wbr[j] * __shfl(LGr, w * 8 + j);
            red[w * 64 + l] = pv;
        }
        __syncthreads();                           // B2

        // ---- C: all-wave V fold; epilogue with shfl'd LG/V; MFMA pipeline --
        float vr = g4v;
        #pragma unroll
        for (int ww = 0; ww < 8; ++ww) vr += red[ww * 64 + l];    // V[d=l]
        // prefetch G for t+1 (t <= L-2 so index valid)
        g2v = G2[(b * L + t + 1) * 64 + l];
        g3v = G3[(b * L + t + 1) * 64 + l];
        g4v = G4it[(b * L + t + 1) * 64 + l];

        float2 qv[4];
        #pragma unroll
        for (int st = 0; st < 4; ++st) qv[st] = qP[(w * 4 + st) * 16 + lm];

        f32x4 part[4];
        #pragma unroll
        for (int dt = 0; dt < 4; ++dt) part[dt] = f32x4{0.f, 0.f, 0.f, 0.f};

        #pragma unroll
        for (int dt = 0; dt < 4; ++dt) {
            const int d0 = dt * 16 + lk * 4;
            f32x4 lg4, v4;
            #pragma unroll
            for (int j = 0; j < 4; ++j) {
                lg4[j] = __shfl(LGr, d0 + j);
                v4[j]  = __shfl(vr,  d0 + j);
            }
            #pragma unroll
            for (int st = 0; st < 4; ++st) {
                const int s = (w * 4 + st) * 16 + lm;
                const float qe = qv[st].x;
                const float qq = qv[st].y;
                const f32x4 a  = acc[dt][st];
                const f32x4 ho = hreg[st][dt];
                f32x4 hn;
                hn.x = qe * lg4.x + sigm(a.x + v4.x) * ho.x;
                hn.y = qe * lg4.y + sigm(a.y + v4.y) * ho.y;
                hn.z = qe * lg4.z + sigm(a.z + v4.z) * ho.z;
                hn.w = qe * lg4.w + sigm(a.w + v4.w) * ho.w;
                hreg[st][dt] = hn;
                *(uint2*)&hB[s * 72 + d0] =
                    make_uint2(pack2(hn.x, hn.y), pack2(hn.z, hn.w));
                part[dt] += qq * hn;
            }
        }

        // pipelined MFMA for t+1 (wave-private hB, same-wave RAW ordered)
        if (t < L - 2) {
            short8v bfr[4][2];
            #pragma unroll
            for (int st = 0; st < 4; ++st) {
                const int s = (w * 4 + st) * 16 + lm;
                #pragma unroll
                for (int kc = 0; kc < 2; ++kc)
                    bfr[st][kc] = *(const short8v*)&hB[s * 72 + kc * 32 + lk * 8];
            }
            #pragma unroll
            for (int dt = 0; dt < 4; ++dt)
                #pragma unroll
                for (int st = 0; st < 4; ++st) {
                    f32x4 z = {0.f, 0.f, 0.f, 0.f};
                    z = __builtin_amdgcn_mfma_f32_16x16x32_bf16(afr[dt][0], bfr[st][0], z, 0, 0, 0);
                    z = __builtin_amdgcn_mfma_f32_16x16x32_bf16(afr[dt][1], bfr[st][1], z, 0, 0, 0);
                    acc[dt][st] = z;
                }
        }

        // h_tilde_{t+1} partials: 2-round shfl, 16 writer lanes -> red4
        #pragma unroll
        for (int dt = 0; dt < 4; ++dt)
            #pragma unroll
            for (int i = 0; i < 4; ++i) {
                float v = part[dt][i];
                v += __shfl_xor(v, 1); v += __shfl_xor(v, 2);
                part[dt][i] = v;
            }
        if ((lm & 3) == 0) {
            const int g = w * 4 + (lm >> 2);
            #pragma unroll
            for (int dt = 0; dt < 4; ++dt)
                *(f32x4*)&red4[g * 68 + dt * 16 + lk * 4] = part[dt];
        }
        __syncthreads();                           // B3
    }

    // final fold: h_tilde_99 -> htH[99]
    if (tid < 64) {
        float htd = 0.f;
        #pragma unroll
        for (int g = 0; g < 32; ++g) htd += red4[g * 68 + l];
        htH[99 * 64 + l] = htd;
    }
    __syncthreads();
    // bulk write h_tilde history to global (coalesced)
    for (int i = tid; i < 100 * 64; i += 512)
        hthist[(size_t)(i >> 6) * (B * 64) + b * 64 + (i & 63)] = htH[i];
}

// ---------------- epilogue: y_t for t=1..99 --------------------------------
__global__ __launch_bounds__(64) void k_y(
    const float* __restrict__ hthist, const float* __restrict__ prey,
    const float* __restrict__ W5T, float* __restrict__ pred)
{
    __shared__ float HT[64];
    const int j = blockIdx.x + 1;    // 1..99
    const int b = blockIdx.y;
    const int d = threadIdx.x;
    HT[d] = hthist[(size_t)j * (B * 64) + b * 64 + d];
    __syncthreads();
    float acc = prey[(b * L + j) * 64 + d];
    #pragma unroll 8
    for (int k = 0; k < 64; ++k) acc += W5T[(128 + k) * 64 + d] * HT[k];
    float y = sigm(acc);
    #pragma unroll
    for (int m = 1; m < 64; m <<= 1) y += __shfl_xor(y, m);
    if (d == 0) pred[b * L + j] = y * (1.0f / 64.0f);
}

} // namespace

extern "C" void kernel_launch(void* const* d_in, const int* in_sizes, int n_in,
                              void* d_out, int out_size, void* d_ws, size_t ws_size,
                              hipStream_t stream)
{
    const int*   e_data   = (const int*)d_in[0];
    const int*   a_data   = (const int*)d_in[1];
    const int*   at_data  = (const int*)d_in[2];
    const int*   it_data  = (const int*)d_in[3];
    const float* q_matrix = (const float*)d_in[4];
    const float* h0       = (const float*)d_in[5];
    const float* e_embed  = (const float*)d_in[6];
    const float* at_embed = (const float*)d_in[7];
    const float* it_embed = (const float*)d_in[8];
    const float* W1 = (const float*)d_in[9];  const float* b1 = (const float*)d_in[10];
    const float* W2 = (const float*)d_in[11]; const float* b2 = (const float*)d_in[12];
    const float* W3 = (const float*)d_in[13]; const float* b3 = (const float*)d_in[14];
    const float* W4 = (const float*)d_in[15]; const float* b4 = (const float*)d_in[16];
    const float* W5 = (const float*)d_in[17]; const float* b5 = (const float*)d_in[18];
    float* pred = (float*)d_out;

    float* ws   = (float*)d_ws;
    float* W1T    = ws;                        // 16384
    float* W2T    = W1T    + 16384;            // 16384
    float* W3T    = W2T    + 16384;            // 16384
    float* W4T    = W3T    + 16384;            // 12288
    float* W5T    = W4T    + 12288;            // 12288
    float* allL   = W5T    + 12288;            // 204800
    float* G2     = allL   + 204800;
    float* G3     = G2     + 204800;
    float* G4it   = G3     + 204800;
    float* prey   = G4it   + 204800;
    float* hthist = prey   + 204800;           // L*B*64 = 204800
    // total ~5.2 MB

    hipLaunchKernelGGL(k_init, dim3(64), dim3(256), 0, stream,
                       W1, W2, W3, W4, W5, W1T, W2T, W3T, W4T, W5T, pred);
    hipLaunchKernelGGL(k_all_learning, dim3(B * L / 4), dim3(256), 0, stream,
                       e_data, a_data, at_data, e_embed, at_embed, W1T, b1, allL);
    hipLaunchKernelGGL(k_pre, dim3(B * L / 4), dim3(256), 0, stream,
                       e_data, it_data, e_embed, it_embed, allL,
                       W2T, W3T, W4T, W5T, b2, b3, b4, b5, G2, G3, G4it, prey);
    hipLaunchKernelGGL(k_steps, dim3(B), dim3(512), 0, stream,
                       G2, G3, G4it, W2, W3, W4, q_matrix, e_data, h0, hthist);
    hipLaunchKernelGGL(k_y, dim3(L - 1, B), dim3(64), 0, stream,
                       hthist, prey, W5T, pred);
}

// Round 17
// 727.922 us; speedup vs baseline: 1.5770x; 1.0794x over previous
//
#include <hip/hip_runtime.h>
#include <hip/hip_bf16.h>

namespace {

constexpr int B  = 32;
constexpr int L  = 100;
constexpr int S  = 501;
constexpr int DK = 64;
constexpr int DE = 128;

typedef __attribute__((ext_vector_type(8))) short short8v;   // 8 bf16 (4 VGPR)
typedef __attribute__((ext_vector_type(4))) float f32x4;
typedef unsigned int u32;

__device__ __forceinline__ float sigm(float x) {
    return __fdividef(1.0f, 1.0f + __expf(-x));
}
// fp32 -> bf16 RNE (one-time staging only)
__device__ __forceinline__ unsigned short f2bf(float f) {
    u32 u = __float_as_uint(f);
    u += 0x7FFFu + ((u >> 16) & 1u);
    return (unsigned short)(u >> 16);
}
// pack two fp32 -> u32 of 2 bf16, round-half-up (4 ops; hot path)
__device__ __forceinline__ u32 pack2(float a, float b) {
    const u32 ua = __float_as_uint(a) + 0x8000u;
    const u32 ub = __float_as_uint(b) + 0x8000u;
    return (ua >> 16) | (ub & 0xFFFF0000u);
}

// ---------------- init: transpose weights (k-major) for pre/y, pred[:,0] ---
__global__ __launch_bounds__(256) void k_init(
    const float* __restrict__ W1, const float* __restrict__ W2,
    const float* __restrict__ W3, const float* __restrict__ W4,
    const float* __restrict__ W5,
    float* __restrict__ W1T, float* __restrict__ W2T, float* __restrict__ W3T,
    float* __restrict__ W4T, float* __restrict__ W5T,
    float* __restrict__ pred)
{
    const int idx = blockIdx.x * 256 + threadIdx.x;
    const int st  = gridDim.x * 256;
    for (int i = idx; i < 64 * 256; i += st) {
        int dd = i >> 8, kk = i & 255;
        W1T[kk * 64 + dd] = W1[i];
        W2T[kk * 64 + dd] = W2[i];
        W3T[kk * 64 + dd] = W3[i];
    }
    for (int i = idx; i < 64 * 192; i += st) {
        int dd = i / 192, kk = i % 192;
        W4T[kk * 64 + dd] = W4[i];
        W5T[kk * 64 + dd] = W5[i];
    }
    if (idx < B) pred[idx * L] = 0.0f;
}

// ---------------- all_learning = concat(e,at,a) @ W1^T + b1 ----------------
__global__ __launch_bounds__(256) void k_all_learning(
    const int* __restrict__ e_data, const int* __restrict__ a_data,
    const int* __restrict__ at_data,
    const float* __restrict__ e_embed, const float* __restrict__ at_embed,
    const float* __restrict__ W1T, const float* __restrict__ b1,
    float* __restrict__ allL)
{
    __shared__ float in_s[4][257];
    const int g = threadIdx.x >> 6;
    const int d = threadIdx.x & 63;
    const int row = blockIdx.x * 4 + g;
    const int e  = e_data[row];
    const int at = at_data[row];
    in_s[g][d]       = e_embed[(size_t)e * DE + d];
    in_s[g][64 + d]  = e_embed[(size_t)e * DE + 64 + d];
    in_s[g][128 + d] = at_embed[(size_t)at * DK + d];
    in_s[g][192 + d] = (float)a_data[row];
    __syncthreads();
    float acc = b1[d];
    #pragma unroll 8
    for (int k = 0; k < 256; ++k) acc += W1T[k * 64 + d] * in_s[g][k];
    allL[row * DK + d] = acc;
}

// ---------------- G2,G3 (non-recurrent parts), G4it, prey ------------------
__global__ __launch_bounds__(256) void k_pre(
    const int* __restrict__ e_data, const int* __restrict__ it_data,
    const float* __restrict__ e_embed, const float* __restrict__ it_embed,
    const float* __restrict__ allL,
    const float* __restrict__ W2T, const float* __restrict__ W3T,
    const float* __restrict__ W4T, const float* __restrict__ W5T,
    const float* __restrict__ b2, const float* __restrict__ b3,
    const float* __restrict__ b4, const float* __restrict__ b5,
    float* __restrict__ G2, float* __restrict__ G3,
    float* __restrict__ G4it, float* __restrict__ prey)
{
    __shared__ float lp[4][64], its[4][64], ln[4][64], ee[4][128];
    const int g = threadIdx.x >> 6;
    const int d = threadIdx.x & 63;
    const int row = blockIdx.x * 4 + g;
    const int t = row % L;
    lp[g][d]  = (t == 0) ? 0.0f : allL[(row - 1) * 64 + d];
    its[g][d] = it_embed[(size_t)it_data[row] * 64 + d];
    ln[g][d]  = allL[row * 64 + d];
    const int e = e_data[row];
    ee[g][d]      = e_embed[(size_t)e * DE + d];
    ee[g][64 + d] = e_embed[(size_t)e * DE + 64 + d];
    __syncthreads();
    float g2 = b2[d], g3 = b3[d], g4 = b4[d], py = b5[d];
    #pragma unroll 4
    for (int k = 0; k < 64; ++k) {
        const float l0 = lp[g][k], i0 = its[g][k], n0 = ln[g][k];
        g2 += W2T[k * 64 + d] * l0 + W2T[(64 + k) * 64 + d] * i0 + W2T[(128 + k) * 64 + d] * n0;
        g3 += W3T[k * 64 + d] * l0 + W3T[(64 + k) * 64 + d] * i0 + W3T[(128 + k) * 64 + d] * n0;
        g4 += W4T[(128 + k) * 64 + d] * i0;
        py += W5T[k * 64 + d] * ee[g][k] + W5T[(64 + k) * 64 + d] * ee[g][64 + k];
    }
    G2[row * 64 + d]   = g2;
    G3[row * 64 + d]   = g3;
    G4it[row * 64 + d] = g4;
    prey[row * 64 + d] = py;
}

// ---------------- persistent recurrence: one block per BATCH ---------------
// 32 blocks x 512 threads (8 waves). Parallel phasing, 6 barriers/step.
// MFMA software-pipelined one phase ahead (bfr reads + 32 MFMAs issue right
// after the epilogue's wave-private hB writes; acc[4][4] carried across the
// gate phases). red4 rows padded to 68 dwords. pack2 = round-half-up.
// This is the measured optimum of this structure (k_steps = 685 us, r13);
// both principled attacks on its residual (16 waves r15, 3-barrier shfl r16)
// regressed and were reverted.
__global__ __launch_bounds__(512, 1) void k_steps(
    const float* __restrict__ G2, const float* __restrict__ G3,
    const float* __restrict__ G4it,
    const float* __restrict__ W2, const float* __restrict__ W3,
    const float* __restrict__ W4,
    const float* __restrict__ q_matrix, const int* __restrict__ e_data,
    const float* __restrict__ h0, float* __restrict__ hthist)
{
    __shared__ unsigned short hB[512 * 72];   // h mirror bf16 (73728 B)
    __shared__ float2 qP[512];                // {q[e_t], q[e_{t+1}]} (4096 B)
    __shared__ float htH[100 * 64];           // h_tilde history (25600 B)
    __shared__ float htS[64], LGs[64], Vs[64];
    __shared__ float red[512], red2[512];     // gate-dot partials (4096 B)
    __shared__ float red4[32 * 68];           // h_tilde partials, padded (8704 B)
    __shared__ int eRow[104];                 // ~118 KB total

    const int tid = threadIdx.x;
    const int b   = blockIdx.x;
    const int l   = tid & 63;     // lane
    const int w   = tid >> 6;     // wave 0..7
    const int lm  = l & 15;
    const int lk  = l >> 4;
    const int d   = tid & 63;     // gate-phase d index
    const int kg  = tid >> 6;     // gate-phase k group 0..7

    // ---- per-thread gate weight registers ----
    float w2r[8], w3r[8], wbr[8];
    #pragma unroll
    for (int j = 0; j < 8; ++j) {
        w2r[j] = W2[d * 256 + 192 + kg * 8 + j];
        w3r[j] = W3[d * 256 + 192 + kg * 8 + j];
        wbr[j] = W4[d * 192 + 64  + kg * 8 + j];
    }

    // ---- A-fragments: W4a[d][k] bf16, persistent in regs ----
    short8v afr[4][2];
    #pragma unroll
    for (int dt = 0; dt < 4; ++dt)
        #pragma unroll
        for (int kc = 0; kc < 2; ++kc) {
            const float* src = W4 + (size_t)(dt * 16 + lm) * 192 + kc * 32 + lk * 8;
            union { unsigned short us[8]; short8v v; } u;
            #pragma unroll
            for (int j = 0; j < 8; ++j) u.us[j] = f2bf(src[j]);
            afr[dt][kc] = u.v;
        }

    if (tid < L) eRow[tid] = e_data[b * L + tid];

    // ---- h registers + bf16 LDS mirror ----
    f32x4 hreg[4][4];   // [st][dt]: h[s][d0..3], s=(w*4+st)*16+lm, d0=dt*16+lk*4
    #pragma unroll
    for (int st = 0; st < 4; ++st) {
        const int s = (w * 4 + st) * 16 + lm;
        #pragma unroll
        for (int dt = 0; dt < 4; ++dt) {
            const int d0 = dt * 16 + lk * 4;
            f32x4 hv = {0.f, 0.f, 0.f, 0.f};
            if (s < S) hv = *(const f32x4*)(h0 + (size_t)s * 64 + d0);
            hreg[st][dt] = hv;
            *(uint2*)&hB[s * 72 + d0] =
                make_uint2(pack2(hv.x, hv.y), pack2(hv.z, hv.w));
        }
    }

    // ---- MFMA for t=0 (wave-private hB rows; same-wave RAW is ordered) ----
    f32x4 acc[4][4];
    {
        short8v bfr[4][2];
        #pragma unroll
        for (int st = 0; st < 4; ++st) {
            const int s = (w * 4 + st) * 16 + lm;
            #pragma unroll
            for (int kc = 0; kc < 2; ++kc)
                bfr[st][kc] = *(const short8v*)&hB[s * 72 + kc * 32 + lk * 8];
        }
        #pragma unroll
        for (int dt = 0; dt < 4; ++dt)
            #pragma unroll
            for (int st = 0; st < 4; ++st) {
                f32x4 z = {0.f, 0.f, 0.f, 0.f};
                z = __builtin_amdgcn_mfma_f32_16x16x32_bf16(afr[dt][0], bfr[st][0], z, 0, 0, 0);
                z = __builtin_amdgcn_mfma_f32_16x16x32_bf16(afr[dt][1], bfr[st][1], z, 0, 0, 0);
                acc[dt][st] = z;
            }
    }
    __syncthreads();                               // eRow ready

    // ---- prologue: qP = {q[e0], q[e1]}; prefetch G[t=0] ----
    {
        const float q0 = (tid < S) ? q_matrix[(size_t)eRow[0] * S + tid] : 0.f;
        const float q1 = (tid < S) ? q_matrix[(size_t)eRow[1] * S + tid] : 0.f;
        qP[tid] = make_float2(q0, q1);
    }
    float g2v = 0.f, g3v = 0.f, g4v = 0.f;
    if (tid < 64) {
        g2v = G2[(b * L) * 64 + l];
        g3v = G3[(b * L) * 64 + l];
        g4v = G4it[(b * L) * 64 + l];
    }
    __syncthreads();                               // qP ready

    // ---- h_tilde_0 partials (2-round shfl -> red4) ----
    {
        f32x4 part[4];
        #pragma unroll
        for (int dt = 0; dt < 4; ++dt) part[dt] = f32x4{0.f, 0.f, 0.f, 0.f};
        #pragma unroll
        for (int st = 0; st < 4; ++st) {
            const int s = (w * 4 + st) * 16 + lm;
            const float qe = qP[s].x;
            #pragma unroll
            for (int dt = 0; dt < 4; ++dt) part[dt] += qe * hreg[st][dt];
        }
        #pragma unroll
        for (int dt = 0; dt < 4; ++dt)
            #pragma unroll
            for (int i = 0; i < 4; ++i) {
                float v = part[dt][i];
                v += __shfl_xor(v, 1); v += __shfl_xor(v, 2);
                part[dt][i] = v;
            }
        if ((lm & 3) == 0) {
            const int g = w * 4 + (lm >> 2);
            #pragma unroll
            for (int dt = 0; dt < 4; ++dt)
                *(f32x4*)&red4[g * 68 + dt * 16 + lk * 4] = part[dt];
        }
    }
    __syncthreads();                               // red4 ready (acts as b5)

    float qn_reg = 0.f;   // q[e_{t+2}] row element (loaded in-loop)

    // ---------------- 99 steps ----------------
    for (int t = 0; t < L - 1; ++t) {
        // P6 (wave 0): fold h_tilde_t -> htS, htH
        if (tid < 64) {
            float htd = 0.f;
            #pragma unroll
            for (int g = 0; g < 32; ++g) htd += red4[g * 68 + l];
            htS[l] = htd;
            htH[t * 64 + l] = htd;
        }
        __syncthreads();                           // b6

        // P1: qP shift + q prefetch (all); gate partials (all)
        if (t > 0) {
            const float2 qold = qP[tid];
            qP[tid] = make_float2(qold.y, qn_reg);
        }
        {
            const int tn = (t + 2 < L) ? t + 2 : L - 1;
            qn_reg = (tid < S) ? q_matrix[(size_t)eRow[tn] * S + tid] : 0.f;
        }
        {
            const f32x4 h4a = *(const f32x4*)&htS[kg * 8];
            const f32x4 h4b = *(const f32x4*)&htS[kg * 8 + 4];
            float p2 = 0.f, p3 = 0.f;
            #pragma unroll
            for (int j = 0; j < 4; ++j) {
                p2 += w2r[j] * h4a[j] + w2r[4 + j] * h4b[j];
                p3 += w3r[j] * h4a[j] + w3r[4 + j] * h4b[j];
            }
            red[kg * 64 + d]  = p2;
            red2[kg * 64 + d] = p3;
        }
        __syncthreads();                           // b1

        // P2 (wave 0): LG
        if (tid < 64) {
            float g2 = g2v, g3 = g3v;
            #pragma unroll
            for (int ww = 0; ww < 8; ++ww) { g2 += red[ww * 64 + d]; g3 += red2[ww * 64 + d]; }
            LGs[d] = sigm(g3) * (tanhf(g2) + 1.0f) * 0.5f;
        }
        __syncthreads();                           // b2

        // P3 (all): W4b @ LG partials
        {
            const f32x4 l4a = *(const f32x4*)&LGs[kg * 8];
            const f32x4 l4b = *(const f32x4*)&LGs[kg * 8 + 4];
            float pv = 0.f;
            #pragma unroll
            for (int j = 0; j < 4; ++j)
                pv += wbr[j] * l4a[j] + wbr[4 + j] * l4b[j];
            red[kg * 64 + d] = pv;
        }
        __syncthreads();                           // b3

        // P4 (wave 0): Vs fold + G prefetch for next step
        if (tid < 64) {
            float v = g4v;
            #pragma unroll
            for (int ww = 0; ww < 8; ++ww) v += red[ww * 64 + d];
            Vs[d] = v;
            g2v = G2[(b * L + t + 1) * 64 + l];
            g3v = G3[(b * L + t + 1) * 64 + l];
            g4v = G4it[(b * L + t + 1) * 64 + l];
        }
        __syncthreads();                           // b4

        // P5: epilogue (acc precomputed) -> h update, hB writes, partials
        float2 qv[4];
        #pragma unroll
        for (int st = 0; st < 4; ++st) qv[st] = qP[(w * 4 + st) * 16 + lm];

        f32x4 part[4];
        #pragma unroll
        for (int dt = 0; dt < 4; ++dt) part[dt] = f32x4{0.f, 0.f, 0.f, 0.f};

        #pragma unroll
        for (int dt = 0; dt < 4; ++dt) {
            const int d0 = dt * 16 + lk * 4;
            const f32x4 lg4 = *(const f32x4*)&LGs[d0];
            const f32x4 v4  = *(const f32x4*)&Vs[d0];
            #pragma unroll
            for (int st = 0; st < 4; ++st) {
                const int s = (w * 4 + st) * 16 + lm;
                const float qe = qv[st].x;
                const float qq = qv[st].y;
                const f32x4 a  = acc[dt][st];
                const f32x4 ho = hreg[st][dt];
                f32x4 hn;
                hn.x = qe * lg4.x + sigm(a.x + v4.x) * ho.x;
                hn.y = qe * lg4.y + sigm(a.y + v4.y) * ho.y;
                hn.z = qe * lg4.z + sigm(a.z + v4.z) * ho.z;
                hn.w = qe * lg4.w + sigm(a.w + v4.w) * ho.w;
                hreg[st][dt] = hn;
                *(uint2*)&hB[s * 72 + d0] =
                    make_uint2(pack2(hn.x, hn.y), pack2(hn.z, hn.w));
                part[dt] += qq * hn;
            }
        }

        // P5b: next step's MFMA (wave-private hB, no barrier needed)
        if (t < L - 2) {
            short8v bfr[4][2];
            #pragma unroll
            for (int st = 0; st < 4; ++st) {
                const int s = (w * 4 + st) * 16 + lm;
                #pragma unroll
                for (int kc = 0; kc < 2; ++kc)
                    bfr[st][kc] = *(const short8v*)&hB[s * 72 + kc * 32 + lk * 8];
            }
            #pragma unroll
            for (int dt = 0; dt < 4; ++dt)
                #pragma unroll
                for (int st = 0; st < 4; ++st) {
                    f32x4 z = {0.f, 0.f, 0.f, 0.f};
                    z = __builtin_amdgcn_mfma_f32_16x16x32_bf16(afr[dt][0], bfr[st][0], z, 0, 0, 0);
                    z = __builtin_amdgcn_mfma_f32_16x16x32_bf16(afr[dt][1], bfr[st][1], z, 0, 0, 0);
                    acc[dt][st] = z;
                }
        }

        // h_tilde_{t+1} partials: 2-round shfl, 16 writer lanes -> red4
        #pragma unroll
        for (int dt = 0; dt < 4; ++dt)
            #pragma unroll
            for (int i = 0; i < 4; ++i) {
                float v = part[dt][i];
                v += __shfl_xor(v, 1); v += __shfl_xor(v, 2);
                part[dt][i] = v;
            }
        if ((lm & 3) == 0) {
            const int g = w * 4 + (lm >> 2);
            #pragma unroll
            for (int dt = 0; dt < 4; ++dt)
                *(f32x4*)&red4[g * 68 + dt * 16 + lk * 4] = part[dt];
        }
        __syncthreads();                           // b5
    }

    // final fold: h_tilde_99 -> htH[99]
    if (tid < 64) {
        float htd = 0.f;
        #pragma unroll
        for (int g = 0; g < 32; ++g) htd += red4[g * 68 + l];
        htH[99 * 64 + l] = htd;
    }
    __syncthreads();
    // bulk write h_tilde history to global (coalesced)
    for (int i = tid; i < 100 * 64; i += 512)
        hthist[(size_t)(i >> 6) * (B * 64) + b * 64 + (i & 63)] = htH[i];
}

// ---------------- epilogue: y_t for t=1..99 --------------------------------
__global__ __launch_bounds__(64) void k_y(
    const float* __restrict__ hthist, const float* __restrict__ prey,
    const float* __restrict__ W5T, float* __restrict__ pred)
{
    __shared__ float HT[64];
    const int j = blockIdx.x + 1;    // 1..99
    const int b = blockIdx.y;
    const int d = threadIdx.x;
    HT[d] = hthist[(size_t)j * (B * 64) + b * 64 + d];
    __syncthreads();
    float acc = prey[(b * L + j) * 64 + d];
    #pragma unroll 8
    for (int k = 0; k < 64; ++k) acc += W5T[(128 + k) * 64 + d] * HT[k];
    float y = sigm(acc);
    #pragma unroll
    for (int m = 1; m < 64; m <<= 1) y += __shfl_xor(y, m);
    if (d == 0) pred[b * L + j] = y * (1.0f / 64.0f);
}

} // namespace

extern "C" void kernel_launch(void* const* d_in, const int* in_sizes, int n_in,
                              void* d_out, int out_size, void* d_ws, size_t ws_size,
                              hipStream_t stream)
{
    const int*   e_data   = (const int*)d_in[0];
    const int*   a_data   = (const int*)d_in[1];
    const int*   at_data  = (const int*)d_in[2];
    const int*   it_data  = (const int*)d_in[3];
    const float* q_matrix = (const float*)d_in[4];
    const float* h0       = (const float*)d_in[5];
    const float* e_embed  = (const float*)d_in[6];
    const float* at_embed = (const float*)d_in[7];
    const float* it_embed = (const float*)d_in[8];
    const float* W1 = (const float*)d_in[9];  const float* b1 = (const float*)d_in[10];
    const float* W2 = (const float*)d_in[11]; const float* b2 = (const float*)d_in[12];
    const float* W3 = (const float*)d_in[13]; const float* b3 = (const float*)d_in[14];
    const float* W4 = (const float*)d_in[15]; const float* b4 = (const float*)d_in[16];
    const float* W5 = (const float*)d_in[17]; const float* b5 = (const float*)d_in[18];
    float* pred = (float*)d_out;

    float* ws   = (float*)d_ws;
    float* W1T    = ws;                        // 16384
    float* W2T    = W1T    + 16384;            // 16384
    float* W3T    = W2T    + 16384;            // 16384
    float* W4T    = W3T    + 16384;            // 12288
    float* W5T    = W4T    + 12288;            // 12288
    float* allL   = W5T    + 12288;            // 204800
    float* G2     = allL   + 204800;
    float* G3     = G2     + 204800;
    float* G4it   = G3     + 204800;
    float* prey   = G4it   + 204800;
    float* hthist = prey   + 204800;           // L*B*64 = 204800
    // total ~5.2 MB

    hipLaunchKernelGGL(k_init, dim3(64), dim3(256), 0, stream,
                       W1, W2, W3, W4, W5, W1T, W2T, W3T, W4T, W5T, pred);
    hipLaunchKernelGGL(k_all_learning, dim3(B * L / 4), dim3(256), 0, stream,
                       e_data, a_data, at_data, e_embed, at_embed, W1T, b1, allL);
    hipLaunchKernelGGL(k_pre, dim3(B * L / 4), dim3(256), 0, stream,
                       e_data, it_data, e_embed, it_embed, allL,
                       W2T, W3T, W4T, W5T, b2, b3, b4, b5, G2, G3, G4it, prey);
    hipLaunchKernelGGL(k_steps, dim3(B), dim3(512), 0, stream,
                       G2, G3, G4it, W2, W3, W4, q_matrix, e_data, h0, hthist);
    hipLaunchKernelGGL(k_y, dim3(L - 1, B), dim3(64), 0, stream,
                       hthist, prey, W5T, pred);
}